// Round 3
// baseline (686.998 us; speedup 1.0000x reference)
//
#include <hip/hip_runtime.h>

typedef __bf16 bf16_t;
typedef bf16_t bf16x8 __attribute__((ext_vector_type(8)));
typedef bf16_t bf16x4 __attribute__((ext_vector_type(4)));
typedef float f32x16 __attribute__((ext_vector_type(16)));

#define BATCH 16384
#define KDIM  1024
#define NCOLS 9216   // [0,3072) ig | [3072,4096) ii | [4096,5120) ih | [5120,8192) hg | [8192,9216) hh

#define BM 256
#define BN 256
#define BK 32
#define NT (KDIM / BK)   // 32

// ---------------- cast f32 -> bf16 ----------------
__global__ __launch_bounds__(256) void cast_f32_bf16(const float* __restrict__ src,
                                                     bf16_t* __restrict__ dst, int n4) {
  int i = blockIdx.x * 256 + threadIdx.x;
  if (i < n4) {
    float4 v = reinterpret_cast<const float4*>(src)[i];
    bf16x4 o;
    o[0] = (bf16_t)v.x; o[1] = (bf16_t)v.y; o[2] = (bf16_t)v.z; o[3] = (bf16_t)v.w;
    reinterpret_cast<bf16x4*>(dst)[i] = o;
  }
}

// ---------------- bias concat ----------------
__global__ __launch_bounds__(256)
void concat_bias(const float* __restrict__ b_ig, const float* __restrict__ b_ii,
                 const float* __restrict__ b_ih, const float* __restrict__ b_hg,
                 const float* __restrict__ b_hh, float* __restrict__ bcat) {
  int i = blockIdx.x * 256 + threadIdx.x;
  if (i >= NCOLS) return;
  float v;
  if      (i < 3072) v = b_ig[i];
  else if (i < 4096) v = b_ii[i - 3072];
  else if (i < 5120) v = b_ih[i - 4096];
  else if (i < 8192) v = b_hg[i - 5120];
  else               v = b_hh[i - 8192];
  bcat[i] = v;
}

// ---------------- GEMM: 256x256 tile, 8 waves (2Mx4N), 32x32x16 MFMA ----------------
// 3-deep counted-vmcnt pipeline: stage(t+2) issued after the barrier that frees its
// buffer; steady-state wait vmcnt(4). LDS XOR-swizzle slot^=(row&3) applied on the
// pre-swizzled global source (global_load_lds writes linearly) and on ds_read.
__global__ __launch_bounds__(512, 2)
void gemm_preln(const bf16_t* __restrict__ inpb, const bf16_t* __restrict__ hidb,
                const bf16_t* __restrict__ Wcat, const float* __restrict__ bcat,
                bf16_t* __restrict__ preLN, int nbm)
{
  __shared__ alignas(16) bf16_t As[3][BM * BK];
  __shared__ alignas(16) bf16_t Bs[3][BN * BK];

  const int tid  = threadIdx.x;
  const int wid  = tid >> 6;         // 0..7
  const int lane = tid & 63;

  // XCD-aware bijective block swizzle (m204)
  const int nwg = nbm * (NCOLS / BN);
  int orig = blockIdx.x;
  int q = nwg >> 3, r = nwg & 7, xcd = orig & 7, idx = orig >> 3;
  int wg = (xcd < r ? xcd * (q + 1) : r * (q + 1) + (xcd - r) * q) + idx;
  const int bm = wg / (NCOLS / BN);
  const int bn = wg % (NCOLS / BN);

  const int row0 = bm * BM;
  const int col0 = bn * BN;
  const bf16_t* __restrict__ act = (col0 < 5120) ? inpb : hidb;
  const bf16_t* __restrict__ wgt = Wcat + (size_t)col0 * KDIM;

  const int wr = wid >> 2;           // 0..1 -> rows wr*128
  const int wc = wid & 3;            // 0..3 -> cols wc*64
  const int lr = lane & 31;          // row/col within 32x32 frag
  const int lk = lane >> 5;          // k-half (8 elems)

  f32x16 acc[4][2] = {};

  auto stage = [&](int buf, int kt) {
    const int k0 = kt * BK;
    #pragma unroll
    for (int c = 0; c < 2; ++c) {
      const int e16 = c * 512 + tid;          // 16B unit within [256][32] tile
      const int row = e16 >> 2;
      const int sl  = (e16 & 3) ^ (row & 3);  // inverse-swizzled source slot
      const bf16_t* ga = act + (size_t)(row0 + row) * KDIM + (k0 + sl * 8);
      const bf16_t* gb = wgt + (size_t)row * KDIM + (k0 + sl * 8);
      // wave-uniform LDS dest base; HW adds lane*16
      __builtin_amdgcn_global_load_lds(
          (const __attribute__((address_space(1))) unsigned int*)ga,
          (__attribute__((address_space(3))) unsigned int*)&As[buf][(c * 512 + wid * 64) * 8],
          16, 0, 0);
      __builtin_amdgcn_global_load_lds(
          (const __attribute__((address_space(1))) unsigned int*)gb,
          (__attribute__((address_space(3))) unsigned int*)&Bs[buf][(c * 512 + wid * 64) * 8],
          16, 0, 0);
    }
  };

  // prologue: tiles 0 and 1 in flight (8 loads)
  stage(0, 0);
  stage(1, 1);

  for (int t = 0; t < NT; ++t) {
    // tile t fully landed for THIS wave (newest 4 loads = tile t+1 may remain)
    if (t < NT - 1) asm volatile("s_waitcnt vmcnt(4)" ::: "memory");
    else            asm volatile("s_waitcnt vmcnt(0)" ::: "memory");
    __builtin_amdgcn_s_barrier();              // all waves' tile-t stages landed;
                                               // all waves done reading buf[(t+2)%3]
    asm volatile("" ::: "memory");             // pin LDS reads below the barrier

    if (t + 2 < NT) stage((t + 2) % 3, t + 2); // safe: readers of this buf passed barrier

    const int buf = t % 3;
    bf16x8 a[4][2], b[2][2];
    #pragma unroll
    for (int m = 0; m < 4; ++m)
      #pragma unroll
      for (int ks = 0; ks < 2; ++ks) {
        const int rr = wr * 128 + m * 32 + lr;
        const int sl = (ks * 2 + lk) ^ (rr & 3);
        a[m][ks] = *(const bf16x8*)&As[buf][rr * 32 + sl * 8];
      }
    #pragma unroll
    for (int n = 0; n < 2; ++n)
      #pragma unroll
      for (int ks = 0; ks < 2; ++ks) {
        const int cc = wc * 64 + n * 32 + lr;
        const int sl = (ks * 2 + lk) ^ (cc & 3);
        b[n][ks] = *(const bf16x8*)&Bs[buf][cc * 32 + sl * 8];
      }

    __builtin_amdgcn_s_setprio(1);
    #pragma unroll
    for (int m = 0; m < 4; ++m)
      #pragma unroll
      for (int n = 0; n < 2; ++n)
        #pragma unroll
        for (int ks = 0; ks < 2; ++ks)
          acc[m][n] = __builtin_amdgcn_mfma_f32_32x32x16_bf16(a[m][ks], b[n][ks], acc[m][n], 0, 0, 0);
    __builtin_amdgcn_s_setprio(0);
  }

  // epilogue: bias + bf16 store. C/D 32x32: col=lane&31, row=(reg&3)+8*(reg>>2)+4*(lane>>5)
  #pragma unroll
  for (int n = 0; n < 2; ++n) {
    const int col = col0 + wc * 64 + n * 32 + lr;
    const float bias = bcat[col];
    #pragma unroll
    for (int m = 0; m < 4; ++m) {
      const int rbase = row0 + wr * 128 + m * 32 + 4 * lk;
      #pragma unroll
      for (int reg = 0; reg < 16; ++reg) {
        const int rr = rbase + (reg & 3) + 8 * (reg >> 2);
        preLN[(size_t)rr * NCOLS + col] = (bf16_t)(acc[m][n][reg] + bias);
      }
    }
  }
}

// ---------------- fused LN + gates + combine: single-sweep stats ----------------
__global__ __launch_bounds__(256)
void ln_combine(const bf16_t* __restrict__ preLN, const float* __restrict__ hidden,
                const float* __restrict__ g_ig, const float* __restrict__ be_ig,
                const float* __restrict__ g_hg, const float* __restrict__ be_hg,
                const float* __restrict__ g_ii, const float* __restrict__ be_ii,
                const float* __restrict__ g_ih, const float* __restrict__ be_ih,
                const float* __restrict__ g_hh, const float* __restrict__ be_hh,
                float* __restrict__ out)
{
  __shared__ alignas(16) bf16_t rowbuf[NCOLS];
  __shared__ float wsum[4][10];
  __shared__ float stats[10];
  const int tid = threadIdx.x;
  const int wv  = tid >> 6;
  const int ln  = tid & 63;
  const size_t row = blockIdx.x;
  const bf16_t* __restrict__ src = preLN + row * NCOLS;

  // one sweep: global -> LDS, accumulate per-segment sums in regs.
  // iteration j covers elems [j*1024, (j+1)*1024): segment is compile-time.
  float s1[5] = {0.f, 0.f, 0.f, 0.f, 0.f};
  float s2[5] = {0.f, 0.f, 0.f, 0.f, 0.f};
  #pragma unroll
  for (int j = 0; j < 9; ++j) {
    const int idx = j * 1024 + tid * 4;
    bf16x4 v = *(const bf16x4*)&src[idx];
    *(bf16x4*)&rowbuf[idx] = v;
    const int sg = (j < 3) ? 0 : (j == 3) ? 1 : (j == 4) ? 2 : (j < 8) ? 3 : 4;
    const float f0 = (float)v[0], f1 = (float)v[1], f2 = (float)v[2], f3 = (float)v[3];
    s1[sg] += f0 + f1 + f2 + f3;
    s2[sg] += f0 * f0 + f1 * f1 + f2 * f2 + f3 * f3;
  }
  #pragma unroll
  for (int s = 0; s < 5; ++s)
    #pragma unroll
    for (int off = 32; off; off >>= 1) {
      s1[s] += __shfl_xor(s1[s], off);
      s2[s] += __shfl_xor(s2[s], off);
    }
  if (ln == 0) {
    #pragma unroll
    for (int s = 0; s < 5; ++s) { wsum[wv][s] = s1[s]; wsum[wv][5 + s] = s2[s]; }
  }
  __syncthreads();
  if (tid < 5) {
    const float n = (tid == 0 || tid == 3) ? 3072.f : 1024.f;
    float t1 = wsum[0][tid] + wsum[1][tid] + wsum[2][tid] + wsum[3][tid];
    float t2 = wsum[0][5 + tid] + wsum[1][5 + tid] + wsum[2][5 + tid] + wsum[3][5 + tid];
    float mu = t1 / n;
    float var = t2 / n - mu * mu;
    stats[tid] = mu;
    stats[5 + tid] = rsqrtf(var + 1e-5f);
  }
  __syncthreads();

  const float mu0 = stats[0], r0 = stats[5];
  const float mu1 = stats[1], r1 = stats[6];
  const float mu2 = stats[2], r2 = stats[7];
  const float mu3 = stats[3], r3 = stats[8];
  const float mu4 = stats[4], r4 = stats[9];
  const float* __restrict__ hrow = hidden + row * 1024;

  #pragma unroll
  for (int k = 0; k < 4; ++k) {
    const int c = tid + k * 256;
    float x_igr = (float)rowbuf[c];
    float x_igz = (float)rowbuf[c + 1024];
    float x_igg = (float)rowbuf[c + 2048];
    float x_ii  = (float)rowbuf[3072 + c];
    float x_ih  = (float)rowbuf[4096 + c];
    float x_hgr = (float)rowbuf[5120 + c];
    float x_hgz = (float)rowbuf[6144 + c];
    float x_hgg = (float)rowbuf[7168 + c];
    float x_hh  = (float)rowbuf[8192 + c];

    float pr = (x_igr - mu0) * r0 * g_ig[c]        + be_ig[c]
             + (x_hgr - mu3) * r3 * g_hg[c]        + be_hg[c];
    float pz = (x_igz - mu0) * r0 * g_ig[c + 1024] + be_ig[c + 1024]
             + (x_hgz - mu3) * r3 * g_hg[c + 1024] + be_hg[c + 1024];
    float pg = (x_igg - mu0) * r0 * g_ig[c + 2048] + be_ig[c + 2048]
             + (x_hgg - mu3) * r3 * g_hg[c + 2048] + be_hg[c + 2048];

    float rr = 1.f / (1.f + __expf(-pr));
    float zz = 1.f / (1.f + __expf(-pz));
    float gg = 1.f / (1.f + __expf(-pg));

    float Hx = (x_ii - mu1) * r1 * g_ii[c] + be_ii[c];
    float xh = (x_ih - mu2) * r2 * g_ih[c] + be_ih[c];
    float hh = (x_hh - mu4) * r4 * g_hh[c] + be_hh[c];

    float hm = tanhf((1.f - rr) * xh + rr * hh);
    float h  = hrow[c];
    out[row * 1024 + c] = ((1.f - zz) * h + zz * hm) * (1.f - gg) + gg * Hx;
  }
}

extern "C" void kernel_launch(void* const* d_in, const int* in_sizes, int n_in,
                              void* d_out, int out_size, void* d_ws, size_t ws_size,
                              hipStream_t stream) {
  const float* inp      = (const float*)d_in[0];
  const float* hidden   = (const float*)d_in[1];
  const float* W_i2gate = (const float*)d_in[2];
  const float* b_i2gate = (const float*)d_in[3];
  const float* W_h2gate = (const float*)d_in[4];
  const float* b_h2gate = (const float*)d_in[5];
  const float* W_i2i    = (const float*)d_in[6];
  const float* b_i2i    = (const float*)d_in[7];
  const float* W_i2h    = (const float*)d_in[8];
  const float* b_i2h    = (const float*)d_in[9];
  const float* W_h2h    = (const float*)d_in[10];
  const float* b_h2h    = (const float*)d_in[11];
  const float* g_ig  = (const float*)d_in[12];
  const float* be_ig = (const float*)d_in[13];
  const float* g_hg  = (const float*)d_in[14];
  const float* be_hg = (const float*)d_in[15];
  const float* g_ii  = (const float*)d_in[16];
  const float* be_ii = (const float*)d_in[17];
  const float* g_ih  = (const float*)d_in[18];
  const float* be_ih = (const float*)d_in[19];
  const float* g_hh  = (const float*)d_in[20];
  const float* be_hh = (const float*)d_in[21];
  float* out = (float*)d_out;

  const size_t WCAT_B  = (size_t)NCOLS * KDIM * 2;     // 18,874,368
  const size_t BCAT_B  = (size_t)NCOLS * 4;            // 36,864
  const size_t FIXED_B = WCAT_B + BCAT_B;
  const size_t PER_ROW = 2048 + 2048 + 18432;          // 22,528

  if (ws_size < FIXED_B + PER_ROW * 256) return;       // visible fail, no OOB

  char* ws = (char*)d_ws;
  bf16_t* Wcat = (bf16_t*)ws;
  float*  bcat = (float*)(ws + WCAT_B);
  char*   dyn  = ws + FIXED_B;

  size_t max_rows = (ws_size - FIXED_B) / PER_ROW;
  int chunk = (int)((max_rows / 256) * 256);
  if (chunk > BATCH) chunk = BATCH;

  bf16_t* inpb  = (bf16_t*)dyn;
  bf16_t* hidb  = (bf16_t*)(dyn + (size_t)chunk * 2048);
  bf16_t* preLN = (bf16_t*)(dyn + (size_t)chunk * 4096);

  {
    int n4g = 3072 * 1024 / 4, n4s = 1024 * 1024 / 4;
    cast_f32_bf16<<<(n4g + 255) / 256, 256, 0, stream>>>(W_i2gate, Wcat, n4g);
    cast_f32_bf16<<<(n4s + 255) / 256, 256, 0, stream>>>(W_i2i, Wcat + 3072 * 1024, n4s);
    cast_f32_bf16<<<(n4s + 255) / 256, 256, 0, stream>>>(W_i2h, Wcat + 4096 * 1024, n4s);
    cast_f32_bf16<<<(n4g + 255) / 256, 256, 0, stream>>>(W_h2gate, Wcat + 5120 * 1024, n4g);
    cast_f32_bf16<<<(n4s + 255) / 256, 256, 0, stream>>>(W_h2h, Wcat + 8192 * 1024, n4s);
    concat_bias<<<(NCOLS + 255) / 256, 256, 0, stream>>>(b_i2gate, b_i2i, b_i2h,
                                                         b_h2gate, b_h2h, bcat);
  }

  for (int r0 = 0; r0 < BATCH; r0 += chunk) {
    int cr = BATCH - r0;
    if (cr > chunk) cr = chunk;
    int n4 = cr * KDIM / 4;
    cast_f32_bf16<<<(n4 + 255) / 256, 256, 0, stream>>>(inp + (size_t)r0 * KDIM, inpb, n4);
    cast_f32_bf16<<<(n4 + 255) / 256, 256, 0, stream>>>(hidden + (size_t)r0 * KDIM, hidb, n4);

    int nbm = cr / BM;
    int nwg = nbm * (NCOLS / BN);
    gemm_preln<<<nwg, 512, 0, stream>>>(inpb, hidb, Wcat, bcat, preLN, nbm);

    ln_combine<<<cr, 256, 0, stream>>>(preLN, hidden + (size_t)r0 * KDIM,
                                       g_ig, be_ig, g_hg, be_hg,
                                       g_ii, be_ii, g_ih, be_ih, g_hh, be_hh,
                                       out + (size_t)r0 * KDIM);
  }
}